// Round 5
// baseline (241.069 us; speedup 1.0000x reference)
//
#include <hip/hip_runtime.h>
#include <math.h>

// Problem: inp [B=16, S=4096, D=512] fp32, lengths[16] int32.
// out [B,S,D+1]: channels 0..511 copy inp; channel 512 is
// pe[b,s] = cos(s/max(len_b,1)*pi) if s < len_b else 0.
//
// v4b: v4 with the nontemporal-store compile fix — use a native clang
// ext_vector type (f32x4) instead of HIP's struct float4, which
// __builtin_nontemporal_store rejects.
//
// Structure: m13-copy-shaped persistent stream.
//   - 2048 blocks x 256 thr (8 wg/CU -> full 32 waves/CU), grid-stride.
//   - 2 chunks per thread per iteration, software-pipelined: next
//     iteration's 4 loads issued BEFORE this iteration's funnels/stores.
//   - nontemporal stores: output is write-once streaming; don't churn the
//     LLC serving ~half the input reads.
//
// Funnel recap (verified v3): output chunk q (dwords 4q..4q+3) sources
// input dwords 4q-r..4q+3-r (r = floor(4q/513)); those live in aligned
// input chunks si-1, si (si = q - (r>>2)); combine with funnel shift
// dlt = r&3. PE dword (c==512) sits at component dlt of its chunk; dirty
// chunks (c0 >= 509) patch it with cos and shift the tail by one.

#define PS   4096
#define PDO  513
#define PI_F 3.14159265358979323846f
#define OUT_V4 8404992   // 16*4096*513/4
#define IN_V4  8388608   // 16*4096*512/4
#define TPB   256
#define NBLK  2048
#define ISTR  (2 * TPB * NBLK)                 // chunks per grid-iteration
#define NITER ((OUT_V4 + ISTR - 1) / ISTR)     // 9 (last partial)

typedef float f32x4 __attribute__((ext_vector_type(4)));

struct Chunk { f32x4 cur, prv; int r, c0; };

__device__ __forceinline__ void load_chunk(const f32x4* __restrict__ in4,
                                           int q, Chunk& ch)
{
    const int l0 = q << 2;                                 // out dword idx
    const int r  = (int)__umulhi((unsigned)l0, 8372256u);  // floor(l0/513)
    const int c0 = l0 - r * PDO;                           // 0..512
    const int si = q - (r >> 2);
    int ci = si;     if (ci > IN_V4 - 1) ci = IN_V4 - 1;   // last chunk: cur unused
    int pi = si - 1; if (pi < 0)         pi = 0;           // q=0: prv unused
    ch.cur = in4[ci];
    ch.prv = in4[pi];
    ch.r = r; ch.c0 = c0;
}

__device__ __forceinline__ f32x4 funnel(const Chunk& ch,
                                        const int* __restrict__ lengths)
{
    const int r   = ch.r;
    const int c0  = ch.c0;
    const int dlt = r & 3;

    // X[-4..-1] = prv, X[0..3] = cur; clean out[m] = X[m-dlt]
    const float px = ch.prv.x, py = ch.prv.y, pz = ch.prv.z, pw = ch.prv.w;
    const float cx = ch.cur.x, cy = ch.cur.y, cz = ch.cur.z, cw = ch.cur.w;
    const bool d2 = (dlt & 2) != 0;
    const bool d1 = (dlt & 1) != 0;
    const float Am1 = d2 ? py : pw;
    const float A0  = d2 ? pz : cx;
    const float A1  = d2 ? pw : cy;
    const float A2  = d2 ? cx : cz;
    const float A3  = d2 ? cy : cw;
    float w0 = d1 ? Am1 : A0;
    float w1 = d1 ? A0  : A1;
    float w2 = d1 ? A1  : A2;
    float w3 = d1 ? A2  : A3;

    if (c0 >= 509) {
        // chunk contains the PE dword (c==512) at component mpe = 512-c0
        // (== dlt); components after it belong to row r+1 = clean[m-1].
        const int mpe = 512 - c0;
        const int b   = r >> 12;
        const int s   = r & (PS - 1);
        const int len = lengths[b];
        float pe = 0.0f;
        if (s < len)
            pe = cosf(((float)s / fmaxf((float)len, 1.0f)) * PI_F);
        const float n0 = (mpe == 0) ? pe : w0;
        const float n1 = (mpe == 1) ? pe : ((mpe < 1) ? w0 : w1);
        const float n2 = (mpe == 2) ? pe : ((mpe < 2) ? w1 : w2);
        const float n3 = (mpe == 3) ? pe : w2;
        w0 = n0; w1 = n1; w2 = n2; w3 = n3;
    }

    f32x4 o;
    o.x = w0; o.y = w1; o.z = w2; o.w = w3;
    return o;
}

__global__ __launch_bounds__(TPB) void sinpe_kernel(
    const float* __restrict__ inp,
    const int* __restrict__ lengths,
    float* __restrict__ out)
{
    const f32x4* __restrict__ in4  = (const f32x4*)inp;
    f32x4* __restrict__       out4 = (f32x4*)out;

    int base = blockIdx.x * (2 * TPB) + threadIdx.x;

    Chunk A, B;
    load_chunk(in4, min(base, OUT_V4 - 1), A);
    load_chunk(in4, min(base + TPB, OUT_V4 - 1), B);

#pragma unroll 1
    for (int i = 0; i < NITER; ++i) {
        const int qa = base;
        const int qb = base + TPB;
        const int nb = base + ISTR;

        Chunk nA, nB;
        if (i + 1 < NITER) {
            // prefetch next iteration BEFORE this iteration's stores
            load_chunk(in4, min(nb, OUT_V4 - 1), nA);
            load_chunk(in4, min(nb + TPB, OUT_V4 - 1), nB);
        } else {
            nA = A; nB = B;
        }

        if (qa < OUT_V4) {
            f32x4 o = funnel(A, lengths);
            __builtin_nontemporal_store(o, &out4[qa]);
        }
        if (qb < OUT_V4) {
            f32x4 o = funnel(B, lengths);
            __builtin_nontemporal_store(o, &out4[qb]);
        }

        A = nA; B = nB; base = nb;
    }
}

extern "C" void kernel_launch(void* const* d_in, const int* in_sizes, int n_in,
                              void* d_out, int out_size, void* d_ws, size_t ws_size,
                              hipStream_t stream)
{
    const float* inp     = (const float*)d_in[0];
    const int*   lengths = (const int*)d_in[1];
    float*       out     = (float*)d_out;

    sinpe_kernel<<<NBLK, TPB, 0, stream>>>(inp, lengths, out);
}

// Round 6
// 232.395 us; speedup vs baseline: 1.0373x; 1.0373x over previous
//
#include <hip/hip_runtime.h>
#include <math.h>

// Problem: inp [B=16, S=4096, D=512] fp32, lengths[16] int32.
// out [B,S,D+1]: channels 0..511 copy inp; channel 512 is
// pe[b,s] = cos(s/max(len_b,1)*pi) if s < len_b else 0.
//
// v6: v0's winning block structure (tiny 1-row blocks, fast-dying waves)
// + fully vectorized dwordx4 on BOTH streams, with zero extra baggage:
//   - the output phase within a row is ROW-UNIFORM: a = (-r) & 3
//     (513*r + a + 4t is 16B-aligned). The funnel is a uniform 4-way
//     switch on a (SGPR branch off blockIdx — no divergence, no per-lane
//     division, no LDS, no barrier).
//   - input row is 16B-aligned: vec4 loads in4[t], in4[min(t+1,127)];
//     the 16B overlap between neighbors is L1-absorbed.
//   - interior: 127..128 aligned vec4 stores; head (a dwords) and tail
//     (<=3 dwords incl. the PE channel) scalar; PE cosf paid by 1 lane.
//   - normal stores (v5 showed nontemporal is mildly harmful here).

#define PS   4096
#define PD   512
#define PDO  513
#define PI_F 3.14159265358979323846f
#define NROWS 65536   // 16*4096

__global__ __launch_bounds__(128) void sinpe_kernel(
    const float* __restrict__ inp,
    const int* __restrict__ lengths,
    float* __restrict__ out)
{
    const int r = blockIdx.x;              // global row 0..65535
    const int t = threadIdx.x;             // 0..127

    const float*  __restrict__ in_row  = inp + (size_t)r * PD;
    const float4* __restrict__ in4     = (const float4*)in_row;
    float* __restrict__        out_row = out + (size_t)r * PDO;

    const int a  = (-r) & 3;               // output phase: 513r + a ≡ 0 mod 4
    const int K  = (PDO - a) >> 2;         // # aligned vec4 stores (127 or 128)
    const int tl0 = a + 4 * K;             // first tail dword (510..513)
    const int TL  = PDO - tl0;             // tail count (0..3), incl. PE slot

    // PE value — computed only by the lane that will write channel 512:
    //   a==1 -> vec lane t==127 (patched into component w)
    //   else -> tail lane t == TL-1 (c = 512)
    const bool need_pe = (a == 1) ? (t == 127) : (t == TL - 1);
    float pe = 0.0f;
    if (need_pe) {
        const int b   = r >> 12;           // r / 4096
        const int s   = r & (PS - 1);
        const int len = lengths[b];
        if (s < len)
            pe = cosf(((float)s / fmaxf((float)len, 1.0f)) * PI_F);
    }

    // ---- interior vec4 copy with row-uniform funnel ----
    if (a == 0) {
        // perfect alignment: straight vec4 copy, 128 stores
        const float4 v = in4[t];
        *(float4*)(out_row + 4 * t) = v;
    } else {
        const float4 va = in4[t];
        const float4 vb = in4[min(t + 1, (PD / 4) - 1)];
        float4 w;
        if (a == 1) {
            w.x = va.y; w.y = va.z; w.z = va.w; w.w = vb.x;
            if (t == 127) w.w = pe;            // c = 1+508+3 = 512
        } else if (a == 2) {
            w.x = va.z; w.y = va.w; w.z = vb.x; w.w = vb.y;
        } else {                               // a == 3
            w.x = va.w; w.y = vb.x; w.z = vb.y; w.w = vb.z;
        }
        if (t < K)
            *(float4*)(out_row + a + 4 * t) = w;
        // head: the a unaligned dwords at the row start
        if (t < a)
            out_row[t] = in_row[t];
    }

    // ---- tail: dwords [tl0, 513) — up to 3, last one is the PE channel ----
    if (t < TL) {
        const int c = tl0 + t;
        const float tin = in_row[min(c, PD - 1)];  // no OOB speculation
        out_row[c] = (c == PD) ? pe : tin;
    }
}

extern "C" void kernel_launch(void* const* d_in, const int* in_sizes, int n_in,
                              void* d_out, int out_size, void* d_ws, size_t ws_size,
                              hipStream_t stream)
{
    const float* inp     = (const float*)d_in[0];
    const int*   lengths = (const int*)d_in[1];
    float*       out     = (float*)d_out;

    sinpe_kernel<<<NROWS, 128, 0, stream>>>(inp, lengths, out);
}